// Round 10
// baseline (1177.892 us; speedup 1.0000x reference)
//
#include <hip/hip_runtime.h>
#include <stdint.h>

typedef unsigned long long ull;
typedef float f32x2 __attribute__((ext_vector_type(2)));

#define NBATCH 8
#define NPTS   4096
#define NS     1024
#define NK     16
#define NF     64
#define NO     128

#define FT  256  // fps threads (4 waves, 1 per SIMD)
#define PPT 16   // points per thread

static __device__ __forceinline__ ull umax64(ull a, ull b) { return a > b ? a : b; }

static __device__ __forceinline__ float dist2(const float* plds, int i, float sx,
                                              float sy, float sz) {
  const float dx = plds[i * 3 + 0] - sx;
  const float dy = plds[i * 3 + 1] - sy;
  const float dz = plds[i * 3 + 2] - sz;
  return fmaf(dz, dz, fmaf(dy, dy, dx * dx));
}

// ---------------------------------------------------------------------------
// Fused kernel 1 (unchanged from round 8).
// Blocks 0..7: FPS. Blocks 8..263: stats partial sums.
// ---------------------------------------------------------------------------
__global__ __launch_bounds__(256) void fps_stats_kernel(
    const float* __restrict__ pos, const float* __restrict__ x,
    const float* __restrict__ W, const float* __restrict__ bias,
    int* __restrict__ fps_idx, float* __restrict__ out_pos,
    float* __restrict__ partial) {
#pragma clang fp contract(off)
  const int t = threadIdx.x;
  __shared__ float plds[NPTS * 3];
  __shared__ __align__(16) ull wslot[2][4];
  __shared__ int widx_lds[NS];

  if (blockIdx.x >= 8) {
    const int blk = blockIdx.x - 8;
    const int c = t & 127;
    const int h = t >> 7;
    float* xl = plds;

    const float4* Wv = (const float4*)(W + c * NF);
    float4 w[16];
#pragma unroll
    for (int q = 0; q < 16; ++q) w[q] = Wv[q];
    const float bb = bias[c];

    const float4* src = (const float4*)(x + (size_t)blk * 128 * NF);
    float4* dst = (float4*)xl;
    for (int i = t; i < 128 * NF / 4; i += 256) dst[i] = src[i];
    __syncthreads();

    float s = 0.f, s2 = 0.f;
    for (int r = h * 64; r < h * 64 + 64; ++r) {
      const float4* xr = (const float4*)(xl + r * NF);
      float hh = bb;
#pragma unroll
      for (int q = 0; q < 16; ++q) {
        const float4 xv = xr[q];
        hh = fmaf(xv.x, w[q].x, hh);
        hh = fmaf(xv.y, w[q].y, hh);
        hh = fmaf(xv.z, w[q].z, hh);
        hh = fmaf(xv.w, w[q].w, hh);
      }
      s += hh;
      s2 = fmaf(hh, hh, s2);
    }
    partial[(blk * 2 + h) * 256 + c] = s;
    partial[(blk * 2 + h) * 256 + 128 + c] = s2;
    return;
  }

  const int b = blockIdx.x;
  const float* p = pos + (size_t)b * NPTS * 3;
  {
    const float4* src = (const float4*)p;
    float4* dst = (float4*)plds;
    for (int i = t; i < NPTS * 3 / 4; i += FT) dst[i] = src[i];
  }
  if (t == 0) widx_lds[0] = 0;
  __syncthreads();

  f32x2 px2[PPT / 2], py2[PPT / 2], pz2[PPT / 2], md2[PPT / 2];
#pragma unroll
  for (int jp = 0; jp < PPT / 2; ++jp) {
    const int i0 = t + FT * (2 * jp);
    const int i1 = i0 + FT;
    px2[jp] = (f32x2){plds[3 * i0 + 0], plds[3 * i1 + 0]};
    py2[jp] = (f32x2){plds[3 * i0 + 1], plds[3 * i1 + 1]};
    pz2[jp] = (f32x2){plds[3 * i0 + 2], plds[3 * i1 + 2]};
    md2[jp] = (f32x2){1e10f, 1e10f};
  }

  float lx = plds[0], ly = plds[1], lz = plds[2];

  for (int s = 1; s < NS; ++s) {
    const f32x2 lxv = (f32x2){lx, lx};
    const f32x2 lyv = (f32x2){ly, ly};
    const f32x2 lzv = (f32x2){lz, lz};
    f32x2 acc = (f32x2){0.f, 0.f};
#pragma unroll
    for (int jp = 0; jp < PPT / 2; ++jp) {
      const f32x2 dx = px2[jp] - lxv;  // IEEE f32, numpy order
      const f32x2 dy = py2[jp] - lyv;
      const f32x2 dz = pz2[jp] - lzv;
      const f32x2 xx = dx * dx;
      const f32x2 yy = dy * dy;
      const f32x2 zz = dz * dz;
      const f32x2 sxy = xx + yy;
      const f32x2 d = sxy + zz;        // ((dx²+dy²)+dz²)
      md2[jp] = __builtin_elementwise_min(md2[jp], d);
      acc = __builtin_elementwise_max(acc, md2[jp]);
    }
    float best = fmaxf(acc.x, acc.y);
    int lidx = 0;
#pragma unroll
    for (int jp = 0; jp < PPT / 2; ++jp) {
      if (md2[jp].x == best) lidx = t + FT * (2 * jp);
      if (md2[jp].y == best) lidx = t + FT * (2 * jp) + FT;
    }
#define CARRY_STEP(ctrl)                                                     \
    {                                                                        \
      const float bo = __int_as_float(__builtin_amdgcn_update_dpp(           \
          0, __float_as_int(best), ctrl, 0xf, 0xf, true));                   \
      const int io =                                                         \
          __builtin_amdgcn_update_dpp(0, lidx, ctrl, 0xf, 0xf, true);        \
      if (bo > best) {                                                       \
        best = bo;                                                           \
        lidx = io;                                                           \
      }                                                                      \
    }
    CARRY_STEP(0x111)
    CARRY_STEP(0x112)
    CARRY_STEP(0x114)
    CARRY_STEP(0x118)
    CARRY_STEP(0x142)
    CARRY_STEP(0x143)
#undef CARRY_STEP
    if ((t & 63) == 63)
      wslot[s & 1][t >> 6] = ((ull)__float_as_uint(best) << 32) | (unsigned)lidx;
    __syncthreads();
    const ull* wk = wslot[s & 1];
    const ull kk = umax64(umax64(wk[0], wk[1]), umax64(wk[2], wk[3]));
    const int widx = (int)(kk & 0xFFFFFFFFu);
    lx = plds[3 * widx + 0];
    ly = plds[3 * widx + 1];
    lz = plds[3 * widx + 2];
    if (t == 0) widx_lds[s] = widx;
  }

  __syncthreads();
  for (int i = t; i < NS; i += FT) {
    const int wi = widx_lds[i];
    fps_idx[b * NS + i] = wi;
    out_pos[((size_t)b * NS + i) * 3 + 0] = plds[3 * wi + 0];
    out_pos[((size_t)b * NS + i) * 3 + 1] = plds[3 * wi + 1];
    out_pos[((size_t)b * NS + i) * 3 + 2] = plds[3 * wi + 2];
  }
}

// ---------------------------------------------------------------------------
// Stats reduce (unchanged from round 8).
// ---------------------------------------------------------------------------
__global__ __launch_bounds__(1024) void stats_reduce_kernel(
    const float* __restrict__ partial, const float* __restrict__ gamma,
    const float* __restrict__ beta, float* __restrict__ ab) {
  const int t = threadIdx.x;
  const int c = t & 127;
  const int q = t >> 7;
  __shared__ double sred[1024], s2red[1024];
  double s = 0.0, s2 = 0.0;
#pragma unroll 4
  for (int r = q * 64; r < q * 64 + 64; ++r) {
    s += (double)partial[r * 256 + c];
    s2 += (double)partial[r * 256 + 128 + c];
  }
  sred[t] = s;
  s2red[t] = s2;
  __syncthreads();
  if (t < 128) {
    s = 0.0;
    s2 = 0.0;
#pragma unroll
    for (int qq = 0; qq < 8; ++qq) {
      s += sred[qq * 128 + t];
      s2 += s2red[qq * 128 + t];
    }
    const double n = 32768.0;
    const double mean = s / n;
    const double var = s2 / n - mean * mean;
    const float inv = (float)(1.0 / sqrt(var + 1e-5));
    const float scale = gamma[t] * inv;
    const float shift = beta[t] - (float)mean * scale;
    ab[t] = scale;
    ab[128 + t] = shift;
  }
}

// ---------------------------------------------------------------------------
// knn_gather v3: u64 keys (d_bits<<32 | idx) — all keys DISTINCT by
// construction, so replace-by-equality top-16 is exact (r9's f32-value scheme
// died on f32 birthday collisions). Kept-smallest on u64 also reproduces
// lax.top_k's lower-index tie-break for equal d.
// Block = 16 samples (grid 64 x 8). Threads = 16 samples x 16 chunks.
// LDS: pos floats (48K) | keys[256][16] u64 (32K) = exactly 80K -> 2 blk/CU.
// Phase 2 (t<16): merge column -> writes final 16 keys back into keys[k][t].
// Phase 4: gather tile aliases the dead pos region; idx read from keys.
// ---------------------------------------------------------------------------
__global__ __launch_bounds__(256) void knn_gather_kernel(
    const float* __restrict__ pos, const int* __restrict__ fps_idx,
    const float* __restrict__ x, const float* __restrict__ W,
    const float* __restrict__ bias, const float* __restrict__ ab,
    float* __restrict__ out) {
  __shared__ ull smem[10240];  // 81920 B
  float* plds = (float*)smem;       // 12288 floats (48K), dead after phase 1
  ull* keys = smem + 6144;          // keys[j][s] at keys[j*16+s] (32K)
  const int b = blockIdx.y;
  const int t = threadIdx.x;
  const int s0 = blockIdx.x * 16;

  {
    const float4* src = (const float4*)(pos + (size_t)b * NPTS * 3);
    float4* dst = (float4*)plds;
    for (int i = t; i < NPTS * 3 / 4; i += 256) dst[i] = src[i];
  }
  __syncthreads();

  const int samp = t >> 4;   // 0..15
  const int chunk = t & 15;  // 0..15
  const int sidx = fps_idx[b * NS + s0 + samp];
  const float sx = plds[sidx * 3 + 0];
  const float sy = plds[sidx * 3 + 1];
  const float sz = plds[sidx * 3 + 2];

  // ---- phase 1: per-thread top-16 keys of its 256 candidates ----
  {
    ull k16[16];
#pragma unroll
    for (int k = 0; k < 16; ++k) k16[k] = 0xFFFFFFFF00000000ull | (unsigned)k;
    ull worst = 0xFFFFFFFF0000000Full;
    for (int j = 0; j < 256; ++j) {
      const int i = j * 16 + chunk;
      const float d = dist2(plds, i, sx, sy, sz);
      const ull key = ((ull)__float_as_uint(d) << 32) | (unsigned)i;
      if (key < worst) {
#pragma unroll
        for (int k = 0; k < 16; ++k) k16[k] = (k16[k] == worst) ? key : k16[k];
        ull w01 = umax64(k16[0], k16[1]);
        ull w2 = umax64(umax64(k16[2], k16[3]), umax64(k16[4], k16[5]));
        ull w3 = umax64(umax64(k16[6], k16[7]), umax64(k16[8], k16[9]));
        ull w4 = umax64(umax64(k16[10], k16[11]), umax64(k16[12], k16[13]));
        ull w5 = umax64(k16[14], k16[15]);
        worst = umax64(umax64(w01, w2), umax64(w3, umax64(w4, w5)));
      }
    }
#pragma unroll
    for (int k = 0; k < 16; ++k) keys[(chunk * 16 + k) * 16 + samp] = k16[k];
  }
  __syncthreads();

  // ---- phase 2: thread t<16 merges its sample's 256 keys -> final 16 ----
  if (t < 16) {
    ull best[16];
#pragma unroll
    for (int k = 0; k < 16; ++k)
      best[k] = 0xFFFFFFFF00000000ull | (unsigned)(4096 + k);
    ull w = 0xFFFFFFFF00000000ull | (unsigned)(4096 + 15);
    for (int j = 0; j < 256; ++j) {
      const ull key = keys[j * 16 + t];
      if (key < w) {
#pragma unroll
        for (int q = 0; q < 16; ++q) best[q] = (best[q] == w) ? key : best[q];
        ull a0 = umax64(best[0], best[1]);
        ull a1 = umax64(umax64(best[2], best[3]), umax64(best[4], best[5]));
        ull a2 = umax64(umax64(best[6], best[7]), umax64(best[8], best[9]));
        ull a3 = umax64(umax64(best[10], best[11]), umax64(best[12], best[13]));
        ull a4 = umax64(best[14], best[15]);
        w = umax64(umax64(a0, a1), umax64(a2, umax64(a3, a4)));
      }
    }
    // writeback into own column (this thread finished reading it; other
    // phase-2 threads touch only their own columns) — indices for phase 4
#pragma unroll
    for (int k = 0; k < 16; ++k) keys[k * 16 + t] = best[k];
  }

  // ---- phase 4: gather + MLP + BN + relu + max, 4 passes of 4 samples ----
  const int c2 = t & 63;
  const int g = t >> 6;
  float4 w0[16], w1[16];
  {
    const float4* Wv0 = (const float4*)(W + c2 * NF);
    const float4* Wv1 = (const float4*)(W + (c2 + 64) * NF);
#pragma unroll
    for (int q = 0; q < 16; ++q) {
      w0[q] = Wv0[q];
      w1[q] = Wv1[q];
    }
  }
  const float bb0 = bias[c2], bb1 = bias[c2 + 64];
  const float scale0 = ab[c2], scale1 = ab[c2 + 64];
  const float shift0 = ab[128 + c2], shift1 = ab[128 + c2 + 64];

  float* xtile = (float*)smem;  // aliases dead pos region (64 x 64 f = 16K)
  const float* xb = x + (size_t)b * NPTS * NF;

  for (int pass = 0; pass < 4; ++pass) {
    __syncthreads();  // pass 0: phase-2 writeback visible; else: compute done
    {
      const int r = t & 63;        // row: (sample pass*4+(r>>4), neighbor r&15)
      const int q0 = (t >> 6) * 4; // 4 float4 per thread
      const int idx =
          (int)(keys[(r & 15) * 16 + (pass * 4 + (r >> 4))] & 0xFFFFFFFFu);
      const float4* srow = (const float4*)(xb + (size_t)idx * NF);
      float4* drow = (float4*)(xtile + r * NF);
#pragma unroll
      for (int q = q0; q < q0 + 4; ++q) drow[q] = srow[q];
    }
    __syncthreads();

    float m0 = 0.0f, m1 = 0.0f;  // relu >= 0
#pragma unroll
    for (int k = 0; k < NK; ++k) {
      const float4* xr = (const float4*)(xtile + (g * 16 + k) * NF);
      float h0 = bb0, h1 = bb1;
#pragma unroll
      for (int q = 0; q < 16; ++q) {
        const float4 xv = xr[q];
        h0 = fmaf(xv.x, w0[q].x, h0);
        h0 = fmaf(xv.y, w0[q].y, h0);
        h0 = fmaf(xv.z, w0[q].z, h0);
        h0 = fmaf(xv.w, w0[q].w, h0);
        h1 = fmaf(xv.x, w1[q].x, h1);
        h1 = fmaf(xv.y, w1[q].y, h1);
        h1 = fmaf(xv.z, w1[q].z, h1);
        h1 = fmaf(xv.w, w1[q].w, h1);
      }
      h0 = fmaf(h0, scale0, shift0);
      h1 = fmaf(h1, scale1, shift1);
      h0 = h0 > 0.f ? h0 : 0.f;
      h1 = h1 > 0.f ? h1 : 0.f;
      m0 = m0 > h0 ? m0 : h0;
      m1 = m1 > h1 ? m1 : h1;
    }
    float* o = out + ((size_t)b * NS + s0 + pass * 4 + g) * NO;
    o[c2] = m0;
    o[c2 + 64] = m1;
  }
}

// ---------------------------------------------------------------------------
extern "C" void kernel_launch(void* const* d_in, const int* in_sizes, int n_in,
                              void* d_out, int out_size, void* d_ws, size_t ws_size,
                              hipStream_t stream) {
  const float* x     = (const float*)d_in[0];  // [8,4096,64]
  const float* pos   = (const float*)d_in[1];  // [8,4096,3]
  const float* W     = (const float*)d_in[2];  // [128,64]
  const float* bias  = (const float*)d_in[3];  // [128]
  const float* gamma = (const float*)d_in[4];  // [128]
  const float* beta  = (const float*)d_in[5];  // [128]

  float* out_knn = (float*)d_out;                       // [8,1024,128]
  float* out_pos = out_knn + (size_t)NBATCH * NS * NO;  // [8,1024,3]

  char* ws = (char*)d_ws;
  int* fps_idx   = (int*)(ws);                 // 8*1024 ints    (32KB)
  float* partial = (float*)(ws + (32 << 10));  // 512*256 floats (512KB)
  float* ab      = (float*)(ws + (544 << 10)); // 256 floats

  fps_stats_kernel<<<8 + 256, 256, 0, stream>>>(pos, x, W, bias, fps_idx,
                                                out_pos, partial);
  stats_reduce_kernel<<<1, 1024, 0, stream>>>(partial, gamma, beta, ab);
  knn_gather_kernel<<<dim3(64, NBATCH), 256, 0, stream>>>(pos, fps_idx, x, W,
                                                          bias, ab, out_knn);
}

// Round 11
// 907.347 us; speedup vs baseline: 1.2982x; 1.2982x over previous
//
#include <hip/hip_runtime.h>
#include <stdint.h>

typedef unsigned long long ull;
typedef float f32x2 __attribute__((ext_vector_type(2)));

#define NBATCH 8
#define NPTS   4096
#define NS     1024
#define NK     16
#define NF     64
#define NO     128

#define FT  256
#define PPT 16

static __device__ __forceinline__ ull umax64(ull a, ull b) { return a > b ? a : b; }
static __device__ __forceinline__ ull umin64(ull a, ull b) { return a < b ? a : b; }

static __device__ __forceinline__ float dist2(const float* plds, int i, float sx,
                                              float sy, float sz) {
  const float dx = plds[i * 3 + 0] - sx;
  const float dy = plds[i * 3 + 1] - sy;
  const float dz = plds[i * 3 + 2] - sz;
  return fmaf(dz, dz, fmaf(dy, dy, dx * dx));
}

// u64 min-reduce across the 64-lane wave via DPP; result valid in lane 63.
// bound_ctrl=false + old=self => invalid lanes contribute self (neutral for min).
static __device__ __forceinline__ ull dpp_min_u64(ull v) {
#define STEP(ctrl)                                                            \
  {                                                                           \
    const unsigned lo = (unsigned)v;                                          \
    const unsigned hi = (unsigned)(v >> 32);                                  \
    const unsigned olo = (unsigned)__builtin_amdgcn_update_dpp(               \
        (int)lo, (int)lo, ctrl, 0xf, 0xf, false);                             \
    const unsigned ohi = (unsigned)__builtin_amdgcn_update_dpp(               \
        (int)hi, (int)hi, ctrl, 0xf, 0xf, false);                             \
    const ull o = ((ull)ohi << 32) | olo;                                     \
    v = o < v ? o : v;                                                        \
  }
  STEP(0x111)  // row_shr:1
  STEP(0x112)  // row_shr:2
  STEP(0x114)  // row_shr:4
  STEP(0x118)  // row_shr:8
  STEP(0x142)  // row_bcast15
  STEP(0x143)  // row_bcast31 -> lane 63 = wave min
#undef STEP
  return v;
}

// ---------------------------------------------------------------------------
// Fused kernel 1 (unchanged). Blocks 0..7: FPS. Blocks 8..263: stats partials.
// ---------------------------------------------------------------------------
__global__ __launch_bounds__(256) void fps_stats_kernel(
    const float* __restrict__ pos, const float* __restrict__ x,
    const float* __restrict__ W, const float* __restrict__ bias,
    int* __restrict__ fps_idx, float* __restrict__ out_pos,
    float* __restrict__ partial) {
#pragma clang fp contract(off)
  const int t = threadIdx.x;
  __shared__ float plds[NPTS * 3];
  __shared__ __align__(16) ull wslot[2][4];
  __shared__ int widx_lds[NS];

  if (blockIdx.x >= 8) {
    const int blk = blockIdx.x - 8;
    const int c = t & 127;
    const int h = t >> 7;
    float* xl = plds;

    const float4* Wv = (const float4*)(W + c * NF);
    float4 w[16];
#pragma unroll
    for (int q = 0; q < 16; ++q) w[q] = Wv[q];
    const float bb = bias[c];

    const float4* src = (const float4*)(x + (size_t)blk * 128 * NF);
    float4* dst = (float4*)xl;
    for (int i = t; i < 128 * NF / 4; i += 256) dst[i] = src[i];
    __syncthreads();

    float s = 0.f, s2 = 0.f;
    for (int r = h * 64; r < h * 64 + 64; ++r) {
      const float4* xr = (const float4*)(xl + r * NF);
      float hh = bb;
#pragma unroll
      for (int q = 0; q < 16; ++q) {
        const float4 xv = xr[q];
        hh = fmaf(xv.x, w[q].x, hh);
        hh = fmaf(xv.y, w[q].y, hh);
        hh = fmaf(xv.z, w[q].z, hh);
        hh = fmaf(xv.w, w[q].w, hh);
      }
      s += hh;
      s2 = fmaf(hh, hh, s2);
    }
    partial[(blk * 2 + h) * 256 + c] = s;
    partial[(blk * 2 + h) * 256 + 128 + c] = s2;
    return;
  }

  const int b = blockIdx.x;
  const float* p = pos + (size_t)b * NPTS * 3;
  {
    const float4* src = (const float4*)p;
    float4* dst = (float4*)plds;
    for (int i = t; i < NPTS * 3 / 4; i += FT) dst[i] = src[i];
  }
  if (t == 0) widx_lds[0] = 0;
  __syncthreads();

  f32x2 px2[PPT / 2], py2[PPT / 2], pz2[PPT / 2], md2[PPT / 2];
#pragma unroll
  for (int jp = 0; jp < PPT / 2; ++jp) {
    const int i0 = t + FT * (2 * jp);
    const int i1 = i0 + FT;
    px2[jp] = (f32x2){plds[3 * i0 + 0], plds[3 * i1 + 0]};
    py2[jp] = (f32x2){plds[3 * i0 + 1], plds[3 * i1 + 1]};
    pz2[jp] = (f32x2){plds[3 * i0 + 2], plds[3 * i1 + 2]};
    md2[jp] = (f32x2){1e10f, 1e10f};
  }

  float lx = plds[0], ly = plds[1], lz = plds[2];

  for (int s = 1; s < NS; ++s) {
    const f32x2 lxv = (f32x2){lx, lx};
    const f32x2 lyv = (f32x2){ly, ly};
    const f32x2 lzv = (f32x2){lz, lz};
    f32x2 acc = (f32x2){0.f, 0.f};
#pragma unroll
    for (int jp = 0; jp < PPT / 2; ++jp) {
      const f32x2 dx = px2[jp] - lxv;  // IEEE f32, numpy order
      const f32x2 dy = py2[jp] - lyv;
      const f32x2 dz = pz2[jp] - lzv;
      const f32x2 xx = dx * dx;
      const f32x2 yy = dy * dy;
      const f32x2 zz = dz * dz;
      const f32x2 sxy = xx + yy;
      const f32x2 d = sxy + zz;        // ((dx²+dy²)+dz²)
      md2[jp] = __builtin_elementwise_min(md2[jp], d);
      acc = __builtin_elementwise_max(acc, md2[jp]);
    }
    float best = fmaxf(acc.x, acc.y);
    int lidx = 0;
#pragma unroll
    for (int jp = 0; jp < PPT / 2; ++jp) {
      if (md2[jp].x == best) lidx = t + FT * (2 * jp);
      if (md2[jp].y == best) lidx = t + FT * (2 * jp) + FT;
    }
#define CARRY_STEP(ctrl)                                                     \
    {                                                                        \
      const float bo = __int_as_float(__builtin_amdgcn_update_dpp(           \
          0, __float_as_int(best), ctrl, 0xf, 0xf, true));                   \
      const int io =                                                         \
          __builtin_amdgcn_update_dpp(0, lidx, ctrl, 0xf, 0xf, true);        \
      if (bo > best) {                                                       \
        best = bo;                                                           \
        lidx = io;                                                           \
      }                                                                      \
    }
    CARRY_STEP(0x111)
    CARRY_STEP(0x112)
    CARRY_STEP(0x114)
    CARRY_STEP(0x118)
    CARRY_STEP(0x142)
    CARRY_STEP(0x143)
#undef CARRY_STEP
    if ((t & 63) == 63)
      wslot[s & 1][t >> 6] = ((ull)__float_as_uint(best) << 32) | (unsigned)lidx;
    __syncthreads();
    const ull* wk = wslot[s & 1];
    const ull kk = umax64(umax64(wk[0], wk[1]), umax64(wk[2], wk[3]));
    const int widx = (int)(kk & 0xFFFFFFFFu);
    lx = plds[3 * widx + 0];
    ly = plds[3 * widx + 1];
    lz = plds[3 * widx + 2];
    if (t == 0) widx_lds[s] = widx;
  }

  __syncthreads();
  for (int i = t; i < NS; i += FT) {
    const int wi = widx_lds[i];
    fps_idx[b * NS + i] = wi;
    out_pos[((size_t)b * NS + i) * 3 + 0] = plds[3 * wi + 0];
    out_pos[((size_t)b * NS + i) * 3 + 1] = plds[3 * wi + 1];
    out_pos[((size_t)b * NS + i) * 3 + 2] = plds[3 * wi + 2];
  }
}

// ---------------------------------------------------------------------------
// Stats reduce (unchanged).
// ---------------------------------------------------------------------------
__global__ __launch_bounds__(1024) void stats_reduce_kernel(
    const float* __restrict__ partial, const float* __restrict__ gamma,
    const float* __restrict__ beta, float* __restrict__ ab) {
  const int t = threadIdx.x;
  const int c = t & 127;
  const int q = t >> 7;
  __shared__ double sred[1024], s2red[1024];
  double s = 0.0, s2 = 0.0;
#pragma unroll 4
  for (int r = q * 64; r < q * 64 + 64; ++r) {
    s += (double)partial[r * 256 + c];
    s2 += (double)partial[r * 256 + 128 + c];
  }
  sred[t] = s;
  s2red[t] = s2;
  __syncthreads();
  if (t < 128) {
    s = 0.0;
    s2 = 0.0;
#pragma unroll
    for (int qq = 0; qq < 8; ++qq) {
      s += sred[qq * 128 + t];
      s2 += s2red[qq * 128 + t];
    }
    const double n = 32768.0;
    const double mean = s / n;
    const double var = s2 / n - mean * mean;
    const float inv = (float)(1.0 / sqrt(var + 1e-5));
    const float scale = gamma[t] * inv;
    const float shift = beta[t] - (float)mean * scale;
    ab[t] = scale;
    ab[128 + t] = shift;
  }
}

// ---------------------------------------------------------------------------
// knn_kernel (standalone, for attribution): block = 16 samples, grid 64 x 8.
// LDS 48KB only (keys overlay the dead pos region) -> 3 blocks/CU.
// Phase 1: thread (samp,chunk) scans 256 candidates -> top-16 u64 keys
//   (d_bits<<32|idx, all distinct => equality-replace exact).
// Phase 2: WAVE-PARALLEL merge: wave w owns samples 4w..4w+3; 256 keys live
//   4/lane in regs; 16 rounds of {per-lane min tree, DPP u64 wave-min,
//   shfl broadcast, kill-by-equality}. No 16-active-lane serial merge.
// ---------------------------------------------------------------------------
__global__ __launch_bounds__(256) void knn_kernel(const float* __restrict__ pos,
                                                  const int* __restrict__ fps_idx,
                                                  int* __restrict__ knn_idx) {
  __shared__ float plds[NPTS * 3];  // 48KB; first 32KB reused as key buffer
  const int b = blockIdx.y;
  const int t = threadIdx.x;
  const int s0 = blockIdx.x * 16;

  {
    const float4* src = (const float4*)(pos + (size_t)b * NPTS * 3);
    float4* dst = (float4*)plds;
    for (int i = t; i < NPTS * 3 / 4; i += 256) dst[i] = src[i];
  }
  __syncthreads();

  const int samp = t >> 4;   // 0..15
  const int chunk = t & 15;  // 0..15
  const int sidx = fps_idx[b * NS + s0 + samp];
  const float sx = plds[sidx * 3 + 0];
  const float sy = plds[sidx * 3 + 1];
  const float sz = plds[sidx * 3 + 2];

  // ---- phase 1: per-thread top-16 keys of its 256 candidates ----
  ull k16[16];
#pragma unroll
  for (int k = 0; k < 16; ++k) k16[k] = 0xFFFFFFFF00000000ull | (unsigned)k;
  ull worst = 0xFFFFFFFF0000000Full;
  for (int j = 0; j < 256; ++j) {
    const int i = j * 16 + chunk;
    const float d = dist2(plds, i, sx, sy, sz);
    const ull key = ((ull)__float_as_uint(d) << 32) | (unsigned)i;
    if (key < worst) {
#pragma unroll
      for (int k = 0; k < 16; ++k) k16[k] = (k16[k] == worst) ? key : k16[k];
      ull w01 = umax64(k16[0], k16[1]);
      ull w2 = umax64(umax64(k16[2], k16[3]), umax64(k16[4], k16[5]));
      ull w3 = umax64(umax64(k16[6], k16[7]), umax64(k16[8], k16[9]));
      ull w4 = umax64(umax64(k16[10], k16[11]), umax64(k16[12], k16[13]));
      ull w5 = umax64(k16[14], k16[15]);
      worst = umax64(umax64(w01, w2), umax64(w3, umax64(w4, w5)));
    }
  }
  __syncthreads();  // everyone done reading pos; overlay keys
  ull* kbuf = (ull*)plds;  // kbuf[s*256 + chunk*16 + k], 32KB
  {
    ull* dst = kbuf + samp * 256 + chunk * 16;
#pragma unroll
    for (int k = 0; k < 16; ++k) dst[k] = k16[k];
  }
  __syncthreads();

  // ---- phase 2: wave-parallel extract-min x16 ----
  const int wave = t >> 6;  // 0..3, owns samples 4w..4w+3
  const int lane = t & 63;
  for (int si = 0; si < 4; ++si) {
    const int s = wave * 4 + si;
    const ull* src = kbuf + s * 256 + lane * 4;
    ull a0 = src[0], a1 = src[1], a2 = src[2], a3 = src[3];
    int kwin = 0;
#pragma unroll
    for (int k = 0; k < 16; ++k) {
      const ull mv = umin64(umin64(a0, a1), umin64(a2, a3));
      const ull wmin = dpp_min_u64(mv);
      const ull win = __shfl(wmin, 63, 64);  // broadcast lane 63
      if (lane == k) kwin = (int)(win & 0xFFFFFFFFu);
      // kill the winner (u64 keys unique => exactly one copy dies)
      a0 = (a0 == win) ? ~0ull : a0;
      a1 = (a1 == win) ? ~0ull : a1;
      a2 = (a2 == win) ? ~0ull : a2;
      a3 = (a3 == win) ? ~0ull : a3;
    }
    if (lane < 16)
      knn_idx[((size_t)b * NS + s0 + s) * NK + lane] = kwin;
  }
}

// ---------------------------------------------------------------------------
// gather_kernel (standalone): block = 16 samples (grid 64 x 8), 256 threads.
// LDS 16KB tile; W rows in regs; 4 passes of 4 samples.
// ---------------------------------------------------------------------------
__global__ __launch_bounds__(256) void gather_kernel(
    const float* __restrict__ x, const float* __restrict__ W,
    const float* __restrict__ bias, const float* __restrict__ ab,
    const int* __restrict__ knn_idx, float* __restrict__ out) {
  __shared__ float xtile[64 * NF];  // 16KB
  const int b = blockIdx.y;
  const int t = threadIdx.x;
  const int s0 = blockIdx.x * 16;
  const int c2 = t & 63;
  const int g = t >> 6;

  float4 w0[16], w1[16];
  {
    const float4* Wv0 = (const float4*)(W + c2 * NF);
    const float4* Wv1 = (const float4*)(W + (c2 + 64) * NF);
#pragma unroll
    for (int q = 0; q < 16; ++q) {
      w0[q] = Wv0[q];
      w1[q] = Wv1[q];
    }
  }
  const float bb0 = bias[c2], bb1 = bias[c2 + 64];
  const float scale0 = ab[c2], scale1 = ab[c2 + 64];
  const float shift0 = ab[128 + c2], shift1 = ab[128 + c2 + 64];
  const float* xb = x + (size_t)b * NPTS * NF;

  for (int pass = 0; pass < 4; ++pass) {
    {
      const int r = t & 63;        // row: sample pass*4+(r>>4), neighbor r&15
      const int q0 = (t >> 6) * 4; // 4 float4 per thread
      const int idx =
          knn_idx[((size_t)b * NS + s0 + pass * 4 + (r >> 4)) * NK + (r & 15)];
      const float4* srow = (const float4*)(xb + (size_t)idx * NF);
      float4* drow = (float4*)(xtile + r * NF);
#pragma unroll
      for (int q = q0; q < q0 + 4; ++q) drow[q] = srow[q];
    }
    __syncthreads();

    float m0 = 0.0f, m1 = 0.0f;  // relu >= 0
#pragma unroll
    for (int k = 0; k < NK; ++k) {
      const float4* xr = (const float4*)(xtile + (g * 16 + k) * NF);
      float h0 = bb0, h1 = bb1;
#pragma unroll
      for (int q = 0; q < 16; ++q) {
        const float4 xv = xr[q];
        h0 = fmaf(xv.x, w0[q].x, h0);
        h0 = fmaf(xv.y, w0[q].y, h0);
        h0 = fmaf(xv.z, w0[q].z, h0);
        h0 = fmaf(xv.w, w0[q].w, h0);
        h1 = fmaf(xv.x, w1[q].x, h1);
        h1 = fmaf(xv.y, w1[q].y, h1);
        h1 = fmaf(xv.z, w1[q].z, h1);
        h1 = fmaf(xv.w, w1[q].w, h1);
      }
      h0 = fmaf(h0, scale0, shift0);
      h1 = fmaf(h1, scale1, shift1);
      h0 = h0 > 0.f ? h0 : 0.f;
      h1 = h1 > 0.f ? h1 : 0.f;
      m0 = m0 > h0 ? m0 : h0;
      m1 = m1 > h1 ? m1 : h1;
    }
    float* o = out + ((size_t)b * NS + s0 + pass * 4 + g) * NO;
    o[c2] = m0;
    o[c2 + 64] = m1;
    __syncthreads();  // xtile reuse next pass
  }
}

// ---------------------------------------------------------------------------
extern "C" void kernel_launch(void* const* d_in, const int* in_sizes, int n_in,
                              void* d_out, int out_size, void* d_ws, size_t ws_size,
                              hipStream_t stream) {
  const float* x     = (const float*)d_in[0];  // [8,4096,64]
  const float* pos   = (const float*)d_in[1];  // [8,4096,3]
  const float* W     = (const float*)d_in[2];  // [128,64]
  const float* bias  = (const float*)d_in[3];  // [128]
  const float* gamma = (const float*)d_in[4];  // [128]
  const float* beta  = (const float*)d_in[5];  // [128]

  float* out_knn = (float*)d_out;                       // [8,1024,128]
  float* out_pos = out_knn + (size_t)NBATCH * NS * NO;  // [8,1024,3]

  char* ws = (char*)d_ws;
  int* fps_idx   = (int*)(ws);                 // 8*1024 ints    (32KB)
  float* partial = (float*)(ws + (32 << 10));  // 512*256 floats (512KB)
  int* knn_idx   = (int*)partial;              // aliases partial (dead after reduce)
  float* ab      = (float*)(ws + (544 << 10)); // 256 floats

  fps_stats_kernel<<<8 + 256, 256, 0, stream>>>(pos, x, W, bias, fps_idx,
                                                out_pos, partial);
  stats_reduce_kernel<<<1, 1024, 0, stream>>>(partial, gamma, beta, ab);
  knn_kernel<<<dim3(64, NBATCH), 256, 0, stream>>>(pos, fps_idx, knn_idx);
  gather_kernel<<<dim3(64, NBATCH), 256, 0, stream>>>(x, W, bias, ab, knn_idx,
                                                      out_knn);
}